// Round 9
// baseline (236.184 us; speedup 1.0000x reference)
//
#include <hip/hip_runtime.h>
#include <hip/hip_bf16.h>

typedef short short8 __attribute__((ext_vector_type(8)));
typedef float f32x4 __attribute__((ext_vector_type(4)));
typedef unsigned int uint4v __attribute__((ext_vector_type(4)));

__device__ __forceinline__ short f2bf(float f) {
  unsigned u = __builtin_bit_cast(unsigned, f);
  u += 0x7fffu + ((u >> 16) & 1u);          // RNE
  return (short)(u >> 16);
}
__device__ __forceinline__ float bf2f(short s) {
  unsigned u = ((unsigned)(unsigned short)s) << 16;
  return __builtin_bit_cast(float, u);
}
__device__ __forceinline__ unsigned pk2(float a, float b) {
  __hip_bfloat162 h = __float22bfloat162_rn(float2{a, b});
  unsigned u;
  __builtin_memcpy(&u, &h, 4);
  return u;
}
__device__ __forceinline__ void gl_lds16(const void* g, void* l) {
  __builtin_amdgcn_global_load_lds(
      (const __attribute__((address_space(1))) unsigned int*)g,
      (__attribute__((address_space(3))) unsigned int*)l, 16, 0, 0);
}

// ---------------- fp32 -> bf16 bulk convert: Xb[z][s][k] --------------------
__global__ __launch_bounds__(256) void xc_kernel(
    const float* __restrict__ Q, const float* __restrict__ K,
    const float* __restrict__ V, short* __restrict__ Xb)
{
  const int z = blockIdx.y;
  const float* X = (z == 0) ? Q : (z == 1) ? K : V;
  short* o = Xb + (size_t)z * 32768 * 512;
  const int stride = gridDim.x * 256;
  const int total = 32768 * 512 / 8;
  for (int i = blockIdx.x * 256 + threadIdx.x; i < total; i += stride) {
    const f32x4* p = (const f32x4*)(X + (size_t)i * 8);
    f32x4 a = p[0], b = p[1];
    uint4v s;
    s[0] = pk2(a[0], a[1]); s[1] = pk2(a[2], a[3]);
    s[2] = pk2(b[0], b[1]); s[3] = pk2(b[2], b[3]);
    *(uint4v*)(o + (size_t)i * 8) = s;
  }
}

// ---------------- W transpose + bf16: Wt[z][n][k] (z=0 WQ,1 WK,2 WV) --------
__global__ __launch_bounds__(256) void wt_kernel(
    const float* __restrict__ WQ, const float* __restrict__ WK,
    const float* __restrict__ WV, short* __restrict__ Wt)
{
  const int z = blockIdx.z;
  const float* W = (z == 0) ? WQ : (z == 1) ? WK : WV;
  short* o = Wt + (size_t)z * 512 * 512;
  __shared__ short t[64][65];
  const int k0 = blockIdx.y * 64, n0 = blockIdx.x * 64;
  const int c = threadIdx.x & 63, rb = threadIdx.x >> 6;
#pragma unroll
  for (int p = 0; p < 16; ++p) {
    const int kk = p * 4 + rb;
    t[kk][c] = f2bf(W[(size_t)(k0 + kk) * 512 + n0 + c]);
  }
  __syncthreads();
#pragma unroll
  for (int p = 0; p < 16; ++p) {
    const int nn = p * 4 + rb;
    o[(size_t)(n0 + nn) * 512 + k0 + c] = t[c][nn];
  }
}

// ======= m97-structure GEMM: 128x128 tile, BK=32, both operands gl_lds ======
// proj: z in {0:Q->qp (no bias), 1:K->kp, 2:V->vp}; 3072 blocks
__global__ __launch_bounds__(256) void proj_kernel(
    const short* __restrict__ Xb, const short* __restrict__ Wt,
    const float* __restrict__ bK, const float* __restrict__ bV,
    short* __restrict__ qp, short* __restrict__ kp, short* __restrict__ vp)
{
  const int phys = blockIdx.x;
  const int log_ = (phys & 7) * 384 + (phys >> 3);   // 3072 = 8*384, bijective
  const int z = log_ >> 10;
  const int rem = log_ & 1023;
  const int row0 = (rem >> 2) * 128;
  const int col0 = (rem & 3) * 128;

  const short* X  = Xb + (size_t)z * 32768 * 512;
  const short* Wz = Wt + (size_t)z * 512 * 512;
  short* dst = (z == 0) ? qp : (z == 1) ? kp : vp;

  __shared__ short a_lds[2][128 * 32];
  __shared__ short b_lds[2][128 * 32];

  const int tid = threadIdx.x;
  const int lane = tid & 63, wv = tid >> 6;
  const int wr = wv >> 1, wc = wv & 1;
  const int fr = lane & 15, fg = lane >> 4;

  // staging: thread covers (row srow within 64-half, 8-elem seg), XOR source swizzle
  const int srow = wv * 16 + (lane >> 2);
  const int sswz = ((lane & 3) ^ (srow & 3)) * 8;   // swizzled global k-offset
  const int sdst = (wv * 16) * 32 + lane * 8;       // linear LDS dest

  f32x4 acc[4][4];
#pragma unroll
  for (int i = 0; i < 4; ++i)
#pragma unroll
    for (int j = 0; j < 4; ++j) acc[i][j] = (f32x4){0.f, 0.f, 0.f, 0.f};

  // prologue: tile 0 -> buf 0
#pragma unroll
  for (int i = 0; i < 2; ++i) {
    gl_lds16(X + (size_t)(row0 + i * 64 + srow) * 512 + sswz,
             &a_lds[0][(i * 64) * 32 + sdst]);
    gl_lds16(Wz + (size_t)(col0 + i * 64 + srow) * 512 + sswz,
             &b_lds[0][(i * 64) * 32 + sdst]);
  }
  __syncthreads();

  for (int t = 0; t < 16; ++t) {
    if (t < 15) {                     // prefetch t+1 into other buf
      const int k1 = (t + 1) * 32;
      short* an = a_lds[(t + 1) & 1];
      short* bn = b_lds[(t + 1) & 1];
#pragma unroll
      for (int i = 0; i < 2; ++i) {
        gl_lds16(X + (size_t)(row0 + i * 64 + srow) * 512 + k1 + sswz,
                 &an[(i * 64) * 32 + sdst]);
        gl_lds16(Wz + (size_t)(col0 + i * 64 + srow) * 512 + k1 + sswz,
                 &bn[(i * 64) * 32 + sdst]);
      }
    }
    const short* ac = a_lds[t & 1];
    const short* bc = b_lds[t & 1];
    const int soff = (fg ^ (fr & 3)) * 8;           // swizzled read slot
    short8 af[4], bfv[4];
#pragma unroll
    for (int mi = 0; mi < 4; ++mi)
      af[mi] = *(const short8*)&ac[(wr * 64 + mi * 16 + fr) * 32 + soff];
#pragma unroll
    for (int ni = 0; ni < 4; ++ni)
      bfv[ni] = *(const short8*)&bc[(wc * 64 + ni * 16 + fr) * 32 + soff];
#pragma unroll
    for (int mi = 0; mi < 4; ++mi)
#pragma unroll
      for (int ni = 0; ni < 4; ++ni)
        acc[mi][ni] = __builtin_amdgcn_mfma_f32_16x16x32_bf16(af[mi], bfv[ni], acc[mi][ni], 0, 0, 0);
    __syncthreads();
  }

#pragma unroll
  for (int ni = 0; ni < 4; ++ni) {
    const int gc = col0 + wc * 64 + ni * 16 + fr;
    const float bv = (z == 0) ? 0.0f : (z == 1) ? bK[gc] : bV[gc];
#pragma unroll
    for (int mi = 0; mi < 4; ++mi) {
#pragma unroll
      for (int r = 0; r < 4; ++r) {
        const int gr = row0 + wr * 64 + mi * 16 + fg * 4 + r;
        dst[(size_t)gr * 512 + gc] = f2bf(acc[mi][ni][r] + bv);
      }
    }
  }
}

// ---------------- LN + ktv accumulation (unchanged) -------------------------
#define SC 256
#define TP 264

__global__ __launch_bounds__(256) void ktv_kernel(
    const short* __restrict__ kp, const short* __restrict__ vp,
    const float* __restrict__ pos,
    const float* __restrict__ lnwK, const float* __restrict__ lnbK,
    const float* __restrict__ lnwV, const float* __restrict__ lnbV,
    float* __restrict__ ktv)
{
  const int nh = blockIdx.y;
  const int n = nh >> 4, h = nh & 15;
  const int s0 = blockIdx.x * SC;
  const int tid = threadIdx.x;

  __shared__ short klds[48 * TP];
  __shared__ short vlds[48 * TP];
  __shared__ float lw[2][32], lb[2][32];

  if (tid < 32) {
    lw[0][tid] = lnwK[h * 32 + tid]; lb[0][tid] = lnbK[h * 32 + tid];
    lw[1][tid] = lnwV[h * 32 + tid]; lb[1][tid] = lnbV[h * 32 + tid];
  }
  __syncthreads();

  const size_t rowix = (size_t)n * 8192 + (s0 + tid);
  {
    const short8* src = (const short8*)(kp + rowix * 512 + h * 32);
    short8 r0 = src[0], r1 = src[1], r2 = src[2], r3 = src[3];
    float x[32];
#pragma unroll
    for (int i = 0; i < 8; ++i) { x[i] = bf2f(r0[i]); x[8+i] = bf2f(r1[i]); x[16+i] = bf2f(r2[i]); x[24+i] = bf2f(r3[i]); }
    float mu = 0.f;
#pragma unroll
    for (int i = 0; i < 32; ++i) mu += x[i];
    mu *= (1.f / 32.f);
    float var = 0.f;
#pragma unroll
    for (int i = 0; i < 32; ++i) { float d = x[i] - mu; var += d * d; }
    var *= (1.f / 32.f);
    const float rstd = rsqrtf(var + 1e-5f);
#pragma unroll
    for (int d = 0; d < 32; ++d)
      klds[d * TP + tid] = f2bf((x[d] - mu) * rstd * lw[0][d] + lb[0][d]);
  }
  {
    const short8* src = (const short8*)(vp + rowix * 512 + h * 32);
    short8 r0 = src[0], r1 = src[1], r2 = src[2], r3 = src[3];
    float x[32];
#pragma unroll
    for (int i = 0; i < 8; ++i) { x[i] = bf2f(r0[i]); x[8+i] = bf2f(r1[i]); x[16+i] = bf2f(r2[i]); x[24+i] = bf2f(r3[i]); }
    float mu = 0.f;
#pragma unroll
    for (int i = 0; i < 32; ++i) mu += x[i];
    mu *= (1.f / 32.f);
    float var = 0.f;
#pragma unroll
    for (int i = 0; i < 32; ++i) { float d = x[i] - mu; var += d * d; }
    var *= (1.f / 32.f);
    const float rstd = rsqrtf(var + 1e-5f);
#pragma unroll
    for (int d = 0; d < 32; ++d)
      vlds[d * TP + tid] = f2bf((x[d] - mu) * rstd * lw[1][d] + lb[1][d]);
  }
  {
    const short p0 = f2bf(pos[rowix * 2]);
    const short p1 = f2bf(pos[rowix * 2 + 1]);
    klds[32 * TP + tid] = p0; klds[33 * TP + tid] = p1;
    vlds[32 * TP + tid] = p0; vlds[33 * TP + tid] = p1;
  }
  __syncthreads();

  const int wv = tid >> 6, lane = tid & 63;
  if (wv < 3) {
    const int fr = lane & 15, fg = lane >> 4;
    f32x4 acc[3];
#pragma unroll
    for (int i = 0; i < 3; ++i) acc[i] = (f32x4){0.f, 0.f, 0.f, 0.f};
    for (int kk = 0; kk < SC; kk += 32) {
      short8 a = *(const short8*)&klds[(wv * 16 + fr) * TP + kk + fg * 8];
#pragma unroll
      for (int ni = 0; ni < 3; ++ni) {
        short8 b = *(const short8*)&vlds[(ni * 16 + fr) * TP + kk + fg * 8];
        acc[ni] = __builtin_amdgcn_mfma_f32_16x16x32_bf16(a, b, acc[ni], 0, 0, 0);
      }
    }
#pragma unroll
    for (int ni = 0; ni < 3; ++ni) {
      const int ei = ni * 16 + fr;
      if (ei < 34) {
        const int er = (ei < 32) ? ei + 2 : ei - 32;
#pragma unroll
        for (int r = 0; r < 4; ++r) {
          const int di = wv * 16 + fg * 4 + r;
          if (di < 34) {
            const int dr = (di < 32) ? di + 2 : di - 32;
            atomicAdd(&ktv[((size_t)nh * 34 + dr) * 34 + er], acc[ni][r]);
          }
        }
      }
    }
  }
}

// ---- S-build: St[n][o][m=h*32+j] (bf16, B^T layout for fuse) + Pp3 ---------
__global__ __launch_bounds__(256) void sbuild_kernel(
    const float* __restrict__ ktv, const float* __restrict__ fcW,
    const float* __restrict__ bQ, short* __restrict__ St, float* __restrict__ Pp3)
{
  const int nh = blockIdx.x;
  const int n = nh >> 4, h = nh & 15;
  const int jq = blockIdx.y;            // 0..3 (8 j's each)
  __shared__ float g[34 * 34];
  __shared__ float bq8[8];
  for (int i = threadIdx.x; i < 34 * 34; i += 256)
    g[i] = ktv[(size_t)nh * 34 * 34 + i] * (1.f / 8192.f);
  if (threadIdx.x < 8) bq8[threadIdx.x] = bQ[h * 32 + jq * 8 + threadIdx.x];
  __syncthreads();

  for (int o = threadIdx.x; o < 512; o += 256) {
    float wcol[34];
#pragma unroll
    for (int e = 0; e < 34; ++e) wcol[e] = fcW[(size_t)o * 544 + h * 34 + e];
    float rv = 0.f;
    short* srow = St + ((size_t)n * 512 + o) * 512 + h * 32 + jq * 8;
#pragma unroll
    for (int jj = 0; jj < 8; ++jj) {
      const int j = jq * 8 + jj;
      float s = 0.f;
#pragma unroll
      for (int e = 0; e < 34; ++e) s += g[(j + 2) * 34 + e] * wcol[e];
      srow[jj] = f2bf(s);
      rv += bq8[jj] * s;
    }
    atomicAdd(&Pp3[((size_t)n * 3 + 2) * 512 + o], rv);
    if (jq == 0) {
      float p0 = 0.f, p1 = 0.f;
#pragma unroll
      for (int e = 0; e < 34; ++e) { p0 += g[e] * wcol[e]; p1 += g[34 + e] * wcol[e]; }
      atomicAdd(&Pp3[((size_t)n * 3 + 0) * 512 + o], p0);
      atomicAdd(&Pp3[((size_t)n * 3 + 1) * 512 + o], p1);
    }
  }
}

// ===== fuse: out[n] = qp[n] @ St[n]^T + pos-terms; m97 structure ============
__global__ __launch_bounds__(256) void fuse_kernel(
    const short* __restrict__ qp, const short* __restrict__ St,
    const float* __restrict__ pos, const float* __restrict__ Pp3,
    const float* __restrict__ fcb, float* __restrict__ out)
{
  const int phys = blockIdx.x;
  const int log_ = (phys & 7) * 128 + (phys >> 3);   // 1024 = 8*128
  const int n = log_ >> 8;
  const int rem = log_ & 255;
  const int row0 = (rem >> 2) * 128;
  const int col0 = (rem & 3) * 128;

  const short* A = qp + (size_t)n * 8192 * 512;
  const short* B = St + (size_t)n * 512 * 512;

  __shared__ short a_lds[2][128 * 32];
  __shared__ short b_lds[2][128 * 32];

  const int tid = threadIdx.x;
  const int lane = tid & 63, wv = tid >> 6;
  const int wr = wv >> 1, wc = wv & 1;
  const int fr = lane & 15, fg = lane >> 4;

  const int srow = wv * 16 + (lane >> 2);
  const int sswz = ((lane & 3) ^ (srow & 3)) * 8;
  const int sdst = (wv * 16) * 32 + lane * 8;

  f32x4 acc[4][4];
#pragma unroll
  for (int i = 0; i < 4; ++i)
#pragma unroll
    for (int j = 0; j < 4; ++j) acc[i][j] = (f32x4){0.f, 0.f, 0.f, 0.f};

#pragma unroll
  for (int i = 0; i < 2; ++i) {
    gl_lds16(A + (size_t)(row0 + i * 64 + srow) * 512 + sswz,
             &a_lds[0][(i * 64) * 32 + sdst]);
    gl_lds16(B + (size_t)(col0 + i * 64 + srow) * 512 + sswz,
             &b_lds[0][(i * 64) * 32 + sdst]);
  }
  __syncthreads();

  for (int t = 0; t < 16; ++t) {
    if (t < 15) {
      const int k1 = (t + 1) * 32;
      short* an = a_lds[(t + 1) & 1];
      short* bn = b_lds[(t + 1) & 1];
#pragma unroll
      for (int i = 0; i < 2; ++i) {
        gl_lds16(A + (size_t)(row0 + i * 64 + srow) * 512 + k1 + sswz,
                 &an[(i * 64) * 32 + sdst]);
        gl_lds16(B + (size_t)(col0 + i * 64 + srow) * 512 + k1 + sswz,
                 &bn[(i * 64) * 32 + sdst]);
      }
    }
    const short* ac = a_lds[t & 1];
    const short* bc = b_lds[t & 1];
    const int soff = (fg ^ (fr & 3)) * 8;
    short8 af[4], bfv[4];
#pragma unroll
    for (int mi = 0; mi < 4; ++mi)
      af[mi] = *(const short8*)&ac[(wr * 64 + mi * 16 + fr) * 32 + soff];
#pragma unroll
    for (int ni = 0; ni < 4; ++ni)
      bfv[ni] = *(const short8*)&bc[(wc * 64 + ni * 16 + fr) * 32 + soff];
#pragma unroll
    for (int mi = 0; mi < 4; ++mi)
#pragma unroll
      for (int ni = 0; ni < 4; ++ni)
        acc[mi][ni] = __builtin_amdgcn_mfma_f32_16x16x32_bf16(af[mi], bfv[ni], acc[mi][ni], 0, 0, 0);
    __syncthreads();
  }

  float pp0[4], pp1[4], rv[4];
#pragma unroll
  for (int ni = 0; ni < 4; ++ni) {
    const int gc = col0 + wc * 64 + ni * 16 + fr;
    pp0[ni] = Pp3[((size_t)n * 3 + 0) * 512 + gc];
    pp1[ni] = Pp3[((size_t)n * 3 + 1) * 512 + gc];
    rv[ni]  = Pp3[((size_t)n * 3 + 2) * 512 + gc] + fcb[gc];
  }
#pragma unroll
  for (int mi = 0; mi < 4; ++mi) {
#pragma unroll
    for (int r = 0; r < 4; ++r) {
      const int gr = row0 + wr * 64 + mi * 16 + fg * 4 + r;
      const float* pr = pos + ((size_t)n * 8192 + gr) * 2;
      const float q0 = pr[0], q1 = pr[1];
#pragma unroll
      for (int ni = 0; ni < 4; ++ni) {
        const int gc = col0 + wc * 64 + ni * 16 + fr;
        out[((size_t)n * 8192 + gr) * 512 + gc] =
            acc[mi][ni][r] + pp0[ni] * q0 + pp1[ni] * q1 + rv[ni];
      }
    }
  }
}

// ---------------------------------------------------------------------------
extern "C" void kernel_launch(void* const* d_in, const int* in_sizes, int n_in,
                              void* d_out, int out_size, void* d_ws, size_t ws_size,
                              hipStream_t stream) {
  const float* Q    = (const float*)d_in[0];
  const float* Kin  = (const float*)d_in[1];
  const float* Vin  = (const float*)d_in[2];
  const float* pos  = (const float*)d_in[3];
  const float* WQ   = (const float*)d_in[4];
  const float* WK   = (const float*)d_in[5];
  const float* WV   = (const float*)d_in[6];
  const float* bQ   = (const float*)d_in[7];
  const float* bK   = (const float*)d_in[8];
  const float* bV   = (const float*)d_in[9];
  const float* lnwK = (const float*)d_in[10];
  const float* lnbK = (const float*)d_in[11];
  const float* lnwV = (const float*)d_in[12];
  const float* lnbV = (const float*)d_in[13];
  const float* fcW  = (const float*)d_in[14];
  const float* fcb  = (const float*)d_in[15];

  char* ws = (char*)d_ws;
  const size_t XB_B  = (size_t)3 * 32768 * 512 * 2;  // 100,663,296
  const size_t P_B   = (size_t)32768 * 512 * 2;      //  33,554,432 each
  const size_t KTV_B = (size_t)64 * 34 * 34 * 4;     //     295,936
  const size_t ST_B  = (size_t)4 * 512 * 512 * 2;    //   2,097,152
  const size_t WT_B  = (size_t)3 * 512 * 512 * 2;    //   1,572,864
  const size_t PP_B  = (size_t)4 * 3 * 512 * 4;      //      24,576
  short* Xb  = (short*)ws;
  short* qp  = (short*)(ws + XB_B);
  short* kp  = (short*)(ws + XB_B + P_B);
  short* vp  = (short*)(ws + XB_B + 2 * P_B);
  float* ktv = (float*)(ws + XB_B + 3 * P_B);
  short* St  = (short*)(ws + XB_B + 3 * P_B + KTV_B);
  short* Wt  = (short*)(ws + XB_B + 3 * P_B + KTV_B + ST_B);
  float* Pp3 = (float*)(ws + XB_B + 3 * P_B + KTV_B + ST_B + WT_B);

  (void)hipMemsetAsync(ktv, 0, KTV_B, stream);
  (void)hipMemsetAsync(Pp3, 0, PP_B, stream);
  hipLaunchKernelGGL(xc_kernel, dim3(1024, 3), dim3(256), 0, stream, Q, Kin, Vin, Xb);
  hipLaunchKernelGGL(wt_kernel, dim3(8, 8, 3), dim3(256), 0, stream, WQ, WK, WV, Wt);
  hipLaunchKernelGGL(proj_kernel, dim3(3072), dim3(256), 0, stream,
                     Xb, Wt, bK, bV, qp, kp, vp);
  hipLaunchKernelGGL(ktv_kernel, dim3(32, 64), dim3(256), 0, stream,
                     kp, vp, pos, lnwK, lnbK, lnwV, lnbV, ktv);
  hipLaunchKernelGGL(sbuild_kernel, dim3(64, 4), dim3(256), 0, stream,
                     ktv, fcW, bQ, St, Pp3);
  hipLaunchKernelGGL(fuse_kernel, dim3(1024), dim3(256), 0, stream,
                     qp, St, pos, Pp3, fcb, (float*)d_out);
}